// Round 4
// baseline (149.327 us; speedup 1.0000x reference)
//
#include <hip/hip_runtime.h>
#include <math.h>

// Problem constants (from reference setup_inputs)
#define CDIM 5
constexpr int B_ = 16;
constexpr int C_ = 256;
constexpr int HW_ = 128 * 128;     // 16384 elements per (b,c) plane
constexpr float MOM = 0.1f;

// Channel striping: process 64 channels (x all 16 batches) at a time so the
// stats->norm re-read window (<= ~134 MB) fits in the 256 MiB Infinity Cache.
constexpr int NSTRIPES = 4;
constexpr int CPS = C_ / NSTRIPES;  // 64 channels per stripe

using f32x4 = __attribute__((ext_vector_type(4))) float;

// ---------------------------------------------------------------------------
// Kernel 1: per-plane mean / std for one channel stripe.
// Grid = 16 batches x 64 channels = 1024 blocks, one plane each.
// Normal (caching) loads so the stripe becomes L3-resident.
// ---------------------------------------------------------------------------
__global__ __launch_bounds__(256) void cin_stats(const float* __restrict__ im,
                                                 float* __restrict__ ws_mean,
                                                 float* __restrict__ ws_std,
                                                 int c0) {
    const int ci = blockIdx.x % CPS;
    const int b  = blockIdx.x / CPS;
    const int plane = b * C_ + c0 + ci;

    const f32x4* p4 = (const f32x4*)(im + (size_t)plane * HW_);
    const int t = threadIdx.x;

    float sum = 0.f, sumsq = 0.f;
    #pragma unroll
    for (int it = 0; it < 16; ++it) {
        f32x4 v = p4[it * 256 + t];
        sum   += v.x + v.y + v.z + v.w;
        sumsq += v.x * v.x + v.y * v.y + v.z * v.z + v.w * v.w;
    }

    // wave64 butterfly reduce
    #pragma unroll
    for (int off = 32; off > 0; off >>= 1) {
        sum   += __shfl_down(sum, off, 64);
        sumsq += __shfl_down(sumsq, off, 64);
    }

    __shared__ float s_sum[4], s_sq[4];
    const int wave = t >> 6;
    if ((t & 63) == 0) { s_sum[wave] = sum; s_sq[wave] = sumsq; }
    __syncthreads();

    if (t == 0) {
        float s = s_sum[0] + s_sum[1] + s_sum[2] + s_sum[3];
        float q = s_sq[0] + s_sq[1] + s_sq[2] + s_sq[3];
        float mean = s / (float)HW_;
        // var = (sumsq - N*mean^2)/(N-1) = (q - s*mean)/(N-1)
        float var = fmaxf(q - s * mean, 0.f) / (float)(HW_ - 1);
        ws_mean[plane] = mean;
        ws_std[plane]  = sqrtf(var);
    }
}

// ---------------------------------------------------------------------------
// Kernel 2: normalize one channel stripe.  One block per plane.  Each block
// redundantly computes the batch-scan for its channel (block-uniform scalar
// work: ~130 uniform loads + ~320 FMAs — negligible), derives scale/shift,
// then streams the plane: im reads hit L3 (just loaded by cin_stats of the
// same stripe); out stores are NONTEMPORAL so they don't evict the stripe.
// ---------------------------------------------------------------------------
__global__ __launch_bounds__(256) void cin_norm(const float* __restrict__ im,
                                                const float* __restrict__ running_mean,
                                                const float* __restrict__ running_std,
                                                const int* __restrict__ c_trg,
                                                const int* __restrict__ c_org,
                                                const float* __restrict__ ws_mean,
                                                const float* __restrict__ ws_std,
                                                float* __restrict__ out,
                                                int c0) {
    const int ci = blockIdx.x % CPS;
    const int b  = blockIdx.x / CPS;
    const int c  = c0 + ci;
    const int plane = b * C_ + c;

    // ---- inline batch-scan for channel c (block-uniform) ----
    float rm[2 * CDIM], rs[2 * CDIM];
    #pragma unroll
    for (int r = 0; r < 2 * CDIM; ++r) {
        rm[r] = running_mean[r * C_ + c];
        rs[r] = running_std [r * C_ + c];
    }
    for (int n = 0; n < B_; ++n) {
        const float mn = ws_mean[n * C_ + c];
        const float sd = ws_std [n * C_ + c];
        int bits[CDIM];
        #pragma unroll
        for (int k = 0; k < CDIM; ++k) bits[k] = c_org[n * CDIM + k];
        #pragma unroll
        for (int r = 0; r < 2 * CDIM; ++r) {
            const int k = (r < CDIM) ? r : r - CDIM;
            const bool msk = (r < CDIM) ? (bits[k] != 0) : (bits[k] == 0);
            if (msk) {
                rs[r] = rs[r] * (1.f - MOM) + sd * MOM;
                rm[r] = rm[r] * (1.f - MOM) + mn * MOM;
            }
        }
    }

    // ---- target stats for batch b ----
    float tm = 0.f, ts = 0.f, cnt = 0.f;
    #pragma unroll
    for (int r = 0; r < 2 * CDIM; ++r) {
        const int k = (r < CDIM) ? r : r - CDIM;
        const int bit = c_trg[b * CDIM + k];
        const bool sel = (r < CDIM) ? (bit != 0) : (bit == 0);
        if (sel) { cnt += 1.f; tm += rm[r]; ts += rs[r]; }
    }
    tm /= cnt;
    ts /= cnt;
    const float mean  = ws_mean[plane];
    const float std   = ws_std [plane];
    const float scale = ts / std;
    const float shift = tm - mean * scale;

    // ---- streaming normalize ----
    const f32x4* p4 = (const f32x4*)(im + (size_t)plane * HW_);
    f32x4*       o4 = (f32x4*)(out + (size_t)plane * HW_);
    const int t = threadIdx.x;

    #pragma unroll
    for (int it = 0; it < 16; ++it) {
        f32x4 v = p4[it * 256 + t];
        f32x4 r;
        r.x = fmaf(v.x, scale, shift);
        r.y = fmaf(v.y, scale, shift);
        r.z = fmaf(v.z, scale, shift);
        r.w = fmaf(v.w, scale, shift);
        __builtin_nontemporal_store(r, &o4[it * 256 + t]);
    }
}

// ---------------------------------------------------------------------------
extern "C" void kernel_launch(void* const* d_in, const int* in_sizes, int n_in,
                              void* d_out, int out_size, void* d_ws, size_t ws_size,
                              hipStream_t stream) {
    const float* im           = (const float*)d_in[0];
    const float* running_mean = (const float*)d_in[1];
    const float* running_std  = (const float*)d_in[2];
    const int*   c_trg        = (const int*)d_in[3];
    const int*   c_org        = (const int*)d_in[4];
    float* out = (float*)d_out;

    // Workspace layout (floats): mean[4096] | std[4096]
    float* ws      = (float*)d_ws;
    float* ws_mean = ws;
    float* ws_std  = ws + B_ * C_;

    const int blocks = B_ * CPS;   // 1024 per stripe

    for (int s = 0; s < NSTRIPES; ++s) {
        const int c0 = s * CPS;
        cin_stats<<<blocks, 256, 0, stream>>>(im, ws_mean, ws_std, c0);
        cin_norm <<<blocks, 256, 0, stream>>>(im, running_mean, running_std,
                                              c_trg, c_org, ws_mean, ws_std,
                                              out, c0);
    }
}